// Round 13
// baseline (558.290 us; speedup 1.0000x reference)
//
#include <hip/hip_runtime.h>

#define N_NODES 20000
#define C 64
#define E_EDGES 320000
#define S_SPEC 64
#define R_DIM 8
#define HR 64
#define HEADS 2
#define TE 64
#define NPAIR (E_EDGES/128)      // 2500 blocks, 2 tiles (128 edges) each
#define HPAD 68                  // padded bf16 row stride (k-dim)
#define INV_AVG (1.0f/16.0f)

// fused prep grid roles
#define NB_WR2T 80
#define NB_WPACK 1056            // (64*4096 + 2*4096)/256
#define NB_HIST 1250
#define NB_NODEUP 5000
#define PREP_BLOCKS (NB_WR2T + NB_WPACK + NB_HIST + NB_NODEUP)

// out layout: node_out [0,40000) ; f_s [40000, 1320000) ; f_v [1320000, 5160000)
#define FS_OFF 40000
#define FV_OFF 1320000

typedef short bf16x4 __attribute__((ext_vector_type(4)));
typedef float f32x4  __attribute__((ext_vector_type(4)));

__device__ __forceinline__ unsigned short f2bf(float f){
  unsigned u = __float_as_uint(f);
  u += 0x7fffu + ((u >> 16) & 1u);
  return (unsigned short)(u >> 16);
}
__device__ __forceinline__ float bf2f(unsigned short b){
  return __uint_as_float(((unsigned)b) << 16);
}
__device__ __forceinline__ unsigned packbf(float a, float b){
  return (unsigned)f2bf(a) | ((unsigned)f2bf(b) << 16);
}
__device__ __forceinline__ float unplo(unsigned u){ return __uint_as_float(u << 16); }
__device__ __forceinline__ float unphi(unsigned u){ return __uint_as_float(u & 0xffff0000u); }
__device__ __forceinline__ float phi_f(float x){
  float n = x * 0.5f;
  float s = (n > 0.0f) ? expf(-1.0f/n) : 0.0f;
  return 1.0f / (1.0f + n * s);
}

// ---------------- fused prep: wr2t | wpack | hist | node_up (independent roles) -------
__global__ __launch_bounds__(256) void prep_kernel(
    const float* __restrict__ Wr2, unsigned short* __restrict__ wr2t,
    const float* __restrict__ W_rs, const float* __restrict__ W_rv,
    const float* __restrict__ W_ds, const float* __restrict__ W_dv,
    const float* __restrict__ W_ps, const float* __restrict__ W_pv,
    unsigned* __restrict__ wrp, unsigned* __restrict__ wdp, unsigned* __restrict__ wpp,
    const int* __restrict__ rcv, int* __restrict__ count,
    const float* __restrict__ fs, const float* __restrict__ fv,
    const float* __restrict__ Wus, const float* __restrict__ Wuv,
    ushort4* __restrict__ suv)
{
  const int b = blockIdx.x;
  const int t = threadIdx.x;
  if (b < NB_WR2T){
    int idx = b*256 + t;                  // n*64 + k
    int n = idx >> 6, k = idx & 63;
    wr2t[idx] = f2bf(Wr2[k*320 + n] * INV_AVG);
    return;
  }
  if (b < NB_WR2T + NB_WPACK){
    int idx = (b - NB_WR2T)*256 + t;
    if (idx < S_SPEC*C*C){
      wrp[idx] = packbf(W_rs[idx], W_rv[idx]);
    } else {
      int r2 = idx - S_SPEC*C*C;
      if (r2 < 4096) wdp[r2] = packbf(W_ds[r2], W_dv[r2]);
      else           wpp[r2-4096] = packbf(W_ps[r2-4096], W_pv[r2-4096]);
    }
    return;
  }
  if (b < NB_WR2T + NB_WPACK + NB_HIST){
    int e = (b - NB_WR2T - NB_WPACK)*256 + t;
    atomicAdd(&count[rcv[e]], 1);
    return;
  }
  // node_up role: 4 nodes/block, Wus/Wuv staged in LDS
  {
    __shared__ float wus_l[C*C];    // 16 KB
    __shared__ float wuv_l[C*C];    // 16 KB
    __shared__ float s_l[4][C];
    __shared__ float v_l[4][3][C];
    const int nb = b - (NB_WR2T + NB_WPACK + NB_HIST);
    const int ni = t >> 6;
    const int d  = t & 63;
    const int n  = nb*4 + ni;
    #pragma unroll
    for (int j = 0; j < 16; ++j){
      wus_l[t + 256*j] = Wus[t + 256*j];
      wuv_l[t + 256*j] = Wuv[t + 256*j];
    }
    s_l[ni][d] = fs[n*C + d];
    #pragma unroll
    for (int x = 0; x < 3; ++x) v_l[ni][x][d] = fv[(n*C + d)*3 + x];
    __syncthreads();
    float as = 0.f, a0 = 0.f, a1 = 0.f, a2 = 0.f;
    #pragma unroll 4
    for (int c = 0; c < C; ++c){
      float wsv = wus_l[c*C + d];
      float wvv = wuv_l[c*C + d];
      as += s_l[ni][c] * wsv;
      a0 += v_l[ni][0][c] * wvv;
      a1 += v_l[ni][1][c] * wvv;
      a2 += v_l[ni][2][c] * wvv;
    }
    ushort4 o;
    o.x = f2bf(as); o.y = f2bf(a0); o.z = f2bf(a1); o.w = f2bf(a2);
    suv[(size_t)n*C + d] = o;
  }
}

// ---------------- scan: wave-shuffle version (2 barriers) -----------------------------
__global__ __launch_bounds__(1024) void scan_kernel(const int* __restrict__ count, int* __restrict__ cursor){
  __shared__ int wsum[16];
  const int t = threadIdx.x;
  const int lane = t & 63, wid = t >> 6;
  const int base = t*20;
  int s = 0;
  int loc[20];
  #pragma unroll 4
  for (int i = 0; i < 20; ++i){
    int idx = base+i;
    int v = (idx < N_NODES) ? count[idx] : 0;
    loc[i] = v; s += v;
  }
  // inclusive wave scan of s
  int x = s;
  #pragma unroll
  for (int dlt = 1; dlt < 64; dlt <<= 1){
    int y = __shfl_up(x, dlt);
    if (lane >= dlt) x += y;
  }
  if (lane == 63) wsum[wid] = x;
  __syncthreads();
  if (wid == 0 && lane < 16){
    int w = wsum[lane];
    #pragma unroll
    for (int dlt = 1; dlt < 16; dlt <<= 1){
      int y = __shfl_up(w, dlt);
      if (lane >= dlt) w += y;
    }
    wsum[lane] = w;
  }
  __syncthreads();
  int wpre = (wid > 0) ? wsum[wid-1] : 0;
  int run = wpre + (x - s);            // exclusive prefix for this thread's range
  #pragma unroll 4
  for (int i = 0; i < 20; ++i){
    int idx = base+i;
    if (idx < N_NODES){ cursor[idx] = run; run += loc[i]; }
  }
}

// ---------------- sort pass C: scatter into sorted arrays, u pre-normalized ----------
__global__ __launch_bounds__(256) void scatter_kernel(
    const int* __restrict__ snd, const int* __restrict__ rcv,
    const float* __restrict__ ev, const float* __restrict__ re,
    int* __restrict__ cursor,
    int* __restrict__ snd_s, int* __restrict__ rcv_s,
    float4* __restrict__ u_s, float* __restrict__ re_s){
  int e = blockIdx.x*256 + threadIdx.x;
  int r = rcv[e];
  int pos = atomicAdd(&cursor[r], 1);
  snd_s[pos] = snd[e];
  rcv_s[pos] = r;
  float x = ev[e*3+0], y = ev[e*3+1], z = ev[e*3+2];
  float nr = sqrtf(x*x + y*y + z*z);
  float inv = 1.0f / fmaxf(nr, 1e-9f);
  float4 u4; u4.x = x*inv; u4.y = y*inv; u4.z = z*inv; u4.w = 0.f;
  u_s[pos] = u4;
  const float4* rp = (const float4*)&re[(size_t)e*R_DIM];
  float4 ra = rp[0], rb = rp[1];
  float4* op = (float4*)&re_s[(size_t)pos*R_DIM];
  op[0] = ra; op[1] = rb;
}

// ---------------- K2: MFMA radial GEMM, 2-tile pipeline; INTERLEAVED accumulator ------
// a_sv[n][c][4] = {s, v0, v1, v2}: each flush = 4 CONSECUTIVE atomics -> 256B/group.
__global__ __launch_bounds__(512, 4) void edge_kernel(
    const float4* __restrict__ u_s, const float* __restrict__ re_s,
    const int* __restrict__ snd_s, const int* __restrict__ rcv_s,
    const float* __restrict__ Wr1, const unsigned short* __restrict__ wr2t,
    const ushort4* __restrict__ suv,
    float* __restrict__ a_sv)
{
  __shared__ __align__(16) float Wr1_l[R_DIM*HR];            // 2 KB
  __shared__ __align__(16) unsigned short Wr2T_l[320*HPAD];  // 43.5 KB

  const int t = threadIdx.x;
  const int lane = t & 63;
  const int w = t >> 6;
  const int g  = w >> 1;
  const int h2 = w & 1;
  int b = blockIdx.x;
  int xcd = b & 7, idx = b >> 3;
  const int q = NPAIR >> 3, r = NPAIR & 7;
  int pair = (xcd < r ? xcd*(q+1) : r*(q+1) + (xcd-r)*q) + idx;
  const int e0A = pair * 128;
  const int e0B = e0A + 64;

  Wr1_l[t] = Wr1[t];
  #pragma unroll
  for (int j = 0; j < 10; ++j){
    int i4 = t + 512*j;
    ushort4 v4 = ((const ushort4*)wr2t)[i4];
    int el = i4*4; int n = el >> 6, k = el & 63;
    *(ushort4*)&Wr2T_l[n*HPAD + k] = v4;
  }

  const int arow = g*16 + (lane & 15);
  const int koff = 4*(lane >> 4);
  const int cl = lane & 15;
  const int ebase = g*16 + (lane >> 4)*4;

  float4 raA = ((const float4*)&re_s[(size_t)(e0A + arow)*R_DIM])[0];
  float4 rbA = ((const float4*)&re_s[(size_t)(e0A + arow)*R_DIM])[1];
  float uxA[4], uyA[4], uzA[4]; int snA[4], rcA[4];
  #pragma unroll
  for (int i = 0; i < 4; ++i){
    int e = e0A + ebase + i;
    float4 uu = u_s[e];
    uxA[i]=uu.x; uyA[i]=uu.y; uzA[i]=uu.z;
    snA[i]=snd_s[e]; rcA[i]=rcv_s[e];
  }
  ushort4 gvA[4][2];
  #pragma unroll
  for (int i = 0; i < 4; ++i){
    const ushort4* sp_ = &suv[(size_t)snA[i]*C];
    #pragma unroll
    for (int kk = 0; kk < 2; ++kk) gvA[i][kk] = sp_[(2*h2 + kk)*16 + cl];
  }
  __syncthreads();

  bf16x4 haA[4];
  #pragma unroll
  for (int kt = 0; kt < 4; ++kt){
    short4 tmp;
    #pragma unroll
    for (int j = 0; j < 4; ++j){
      int k = kt*16 + koff + j;
      float acc = raA.x*Wr1_l[0*HR+k] + raA.y*Wr1_l[1*HR+k] + raA.z*Wr1_l[2*HR+k] + raA.w*Wr1_l[3*HR+k]
                + rbA.x*Wr1_l[4*HR+k] + rbA.y*Wr1_l[5*HR+k] + rbA.z*Wr1_l[6*HR+k] + rbA.w*Wr1_l[7*HR+k];
      float sil = acc / (1.0f + expf(-acc));
      ((unsigned short*)&tmp)[j] = f2bf(sil);
    }
    haA[kt] = *(bf16x4*)&tmp;
  }

  float4 raB = ((const float4*)&re_s[(size_t)(e0B + arow)*R_DIM])[0];
  float4 rbB = ((const float4*)&re_s[(size_t)(e0B + arow)*R_DIM])[1];
  float uxB[4], uyB[4], uzB[4]; int snB[4], rcB[4];
  #pragma unroll
  for (int i = 0; i < 4; ++i){
    int e = e0B + ebase + i;
    float4 uu = u_s[e];
    uxB[i]=uu.x; uyB[i]=uu.y; uzB[i]=uu.z;
    snB[i]=snd_s[e]; rcB[i]=rcv_s[e];
  }

  f32x4 accA[10];
  #pragma unroll
  for (int lf = 0; lf < 10; ++lf) accA[lf] = (f32x4){0.f,0.f,0.f,0.f};
  #pragma unroll
  for (int kt = 0; kt < 4; ++kt){
    bf16x4 af = haA[kt];
    #pragma unroll
    for (int lf = 0; lf < 10; ++lf){
      int p = lf >> 1, kk = lf & 1;
      int n = (p*4 + 2*h2 + kk)*16 + cl;
      bf16x4 bf = *(const bf16x4*)&Wr2T_l[n*HPAD + kt*16 + koff];
      accA[lf] = __builtin_amdgcn_mfma_f32_16x16x16bf16_1k(af, bf, accA[lf], 0, 0, 0);
    }
  }

  ushort4 gvB[4][2];
  #pragma unroll
  for (int i = 0; i < 4; ++i){
    const ushort4* sp_ = &suv[(size_t)snB[i]*C];
    #pragma unroll
    for (int kk = 0; kk < 2; ++kk) gvB[i][kk] = sp_[(2*h2 + kk)*16 + cl];
  }

  {
    float ms[2], mv0[2], mv1[2], mv2[2];
    #pragma unroll
    for (int kk = 0; kk < 2; ++kk){ ms[kk]=0.f; mv0[kk]=0.f; mv1[kk]=0.f; mv2[kk]=0.f; }
    int cur = rcA[0];
    #pragma unroll
    for (int i = 0; i < 4; ++i){
      int rc = rcA[i];
      if (rc != cur){
        #pragma unroll
        for (int kk = 0; kk < 2; ++kk){
          int c = (2*h2 + kk)*16 + cl;
          float* dst = &a_sv[((size_t)cur*C + c)*4];
          unsafeAtomicAdd(dst+0, ms[kk]);
          unsafeAtomicAdd(dst+1, mv0[kk]);
          unsafeAtomicAdd(dst+2, mv1[kk]);
          unsafeAtomicAdd(dst+3, mv2[kk]);
          ms[kk]=0.f; mv0[kk]=0.f; mv1[kk]=0.f; mv2[kk]=0.f;
        }
        cur = rc;
      }
      float u0 = uxA[i], u1 = uyA[i], u2 = uzA[i];
      #pragma unroll
      for (int kk = 0; kk < 2; ++kk){
        float se  = bf2f(gvA[i][kk].x);
        float ve0 = bf2f(gvA[i][kk].y);
        float ve1 = bf2f(gvA[i][kk].z);
        float ve2 = bf2f(gvA[i][kk].w);
        float w0 = accA[0*2+kk][i];
        float w1 = accA[1*2+kk][i];
        float w2 = accA[2*2+kk][i];
        float w3 = accA[3*2+kk][i];
        float w4 = accA[4*2+kk][i];
        float dt  = ve0*u0 + ve1*u1 + ve2*u2;
        float cr0 = ve1*u2 - ve2*u1;
        float cr1 = ve2*u0 - ve0*u2;
        float cr2 = ve0*u1 - ve1*u0;
        ms[kk]  += w0*se + w3*dt;
        mv0[kk] += w1*ve0 + w2*u0 + w4*cr0;
        mv1[kk] += w1*ve1 + w2*u1 + w4*cr1;
        mv2[kk] += w1*ve2 + w2*u2 + w4*cr2;
      }
    }
    #pragma unroll
    for (int kk = 0; kk < 2; ++kk){
      int c = (2*h2 + kk)*16 + cl;
      float* dst = &a_sv[((size_t)cur*C + c)*4];
      unsafeAtomicAdd(dst+0, ms[kk]);
      unsafeAtomicAdd(dst+1, mv0[kk]);
      unsafeAtomicAdd(dst+2, mv1[kk]);
      unsafeAtomicAdd(dst+3, mv2[kk]);
    }
  }

  bf16x4 haB[4];
  #pragma unroll
  for (int kt = 0; kt < 4; ++kt){
    short4 tmp;
    #pragma unroll
    for (int j = 0; j < 4; ++j){
      int k = kt*16 + koff + j;
      float acc = raB.x*Wr1_l[0*HR+k] + raB.y*Wr1_l[1*HR+k] + raB.z*Wr1_l[2*HR+k] + raB.w*Wr1_l[3*HR+k]
                + rbB.x*Wr1_l[4*HR+k] + rbB.y*Wr1_l[5*HR+k] + rbB.z*Wr1_l[6*HR+k] + rbB.w*Wr1_l[7*HR+k];
      float sil = acc / (1.0f + expf(-acc));
      ((unsigned short*)&tmp)[j] = f2bf(sil);
    }
    haB[kt] = *(bf16x4*)&tmp;
  }
  f32x4 accB[10];
  #pragma unroll
  for (int lf = 0; lf < 10; ++lf) accB[lf] = (f32x4){0.f,0.f,0.f,0.f};
  #pragma unroll
  for (int kt = 0; kt < 4; ++kt){
    bf16x4 af = haB[kt];
    #pragma unroll
    for (int lf = 0; lf < 10; ++lf){
      int p = lf >> 1, kk = lf & 1;
      int n = (p*4 + 2*h2 + kk)*16 + cl;
      bf16x4 bf = *(const bf16x4*)&Wr2T_l[n*HPAD + kt*16 + koff];
      accB[lf] = __builtin_amdgcn_mfma_f32_16x16x16bf16_1k(af, bf, accB[lf], 0, 0, 0);
    }
  }

  {
    float ms[2], mv0[2], mv1[2], mv2[2];
    #pragma unroll
    for (int kk = 0; kk < 2; ++kk){ ms[kk]=0.f; mv0[kk]=0.f; mv1[kk]=0.f; mv2[kk]=0.f; }
    int cur = rcB[0];
    #pragma unroll
    for (int i = 0; i < 4; ++i){
      int rc = rcB[i];
      if (rc != cur){
        #pragma unroll
        for (int kk = 0; kk < 2; ++kk){
          int c = (2*h2 + kk)*16 + cl;
          float* dst = &a_sv[((size_t)cur*C + c)*4];
          unsafeAtomicAdd(dst+0, ms[kk]);
          unsafeAtomicAdd(dst+1, mv0[kk]);
          unsafeAtomicAdd(dst+2, mv1[kk]);
          unsafeAtomicAdd(dst+3, mv2[kk]);
          ms[kk]=0.f; mv0[kk]=0.f; mv1[kk]=0.f; mv2[kk]=0.f;
        }
        cur = rc;
      }
      float u0 = uxB[i], u1 = uyB[i], u2 = uzB[i];
      #pragma unroll
      for (int kk = 0; kk < 2; ++kk){
        float se  = bf2f(gvB[i][kk].x);
        float ve0 = bf2f(gvB[i][kk].y);
        float ve1 = bf2f(gvB[i][kk].z);
        float ve2 = bf2f(gvB[i][kk].w);
        float w0 = accB[0*2+kk][i];
        float w1 = accB[1*2+kk][i];
        float w2 = accB[2*2+kk][i];
        float w3 = accB[3*2+kk][i];
        float w4 = accB[4*2+kk][i];
        float dt  = ve0*u0 + ve1*u1 + ve2*u2;
        float cr0 = ve1*u2 - ve2*u1;
        float cr1 = ve2*u0 - ve0*u2;
        float cr2 = ve0*u1 - ve1*u0;
        ms[kk]  += w0*se + w3*dt;
        mv0[kk] += w1*ve0 + w2*u0 + w4*cr0;
        mv1[kk] += w1*ve1 + w2*u1 + w4*cr1;
        mv2[kk] += w1*ve2 + w2*u2 + w4*cr2;
      }
    }
    #pragma unroll
    for (int kk = 0; kk < 2; ++kk){
      int c = (2*h2 + kk)*16 + cl;
      float* dst = &a_sv[((size_t)cur*C + c)*4];
      unsafeAtomicAdd(dst+0, ms[kk]);
      unsafeAtomicAdd(dst+1, mv0[kk]);
      unsafeAtomicAdd(dst+2, mv1[kk]);
      unsafeAtomicAdd(dst+3, mv2[kk]);
    }
  }
}

// ---------------- K3: node_post with LDS packed weights + float4 accumulator reads ----
__global__ __launch_bounds__(256) void node_post_kernel(
    const float* __restrict__ a_sv,
    const float* __restrict__ fs_in, const float* __restrict__ fv_in,
    const int* __restrict__ species,
    const unsigned* __restrict__ wrp,
    const unsigned* __restrict__ wdp,
    const unsigned* __restrict__ wpp,
    const float* __restrict__ w1s, const float* __restrict__ w1v,
    const float* __restrict__ w2ss, const float* __restrict__ w2vv, const float* __restrict__ w2sv,
    const float* __restrict__ w_read, float* __restrict__ out)
{
  const int ni = threadIdx.x >> 6;
  const int d  = threadIdx.x & 63;
  const int n  = blockIdx.x*4 + ni;
  const int sp = species[n];
  const int t  = threadIdx.x;
  __shared__ float as_l[4][C];
  __shared__ float av_l[4][3][C];
  __shared__ float si_l[4][C];
  __shared__ float vi_l[4][3][C];
  __shared__ unsigned wdp_l[C*C];   // 16 KB
  __shared__ unsigned wpp_l[C*C];   // 16 KB
  #pragma unroll
  for (int j = 0; j < 16; ++j){
    wdp_l[t + 256*j] = wdp[t + 256*j];
    wpp_l[t + 256*j] = wpp[t + 256*j];
  }
  {
    float4 av = ((const float4*)a_sv)[(size_t)n*C + d];
    as_l[ni][d] = av.x;
    av_l[ni][0][d] = av.y; av_l[ni][1][d] = av.z; av_l[ni][2][d] = av.w;
  }
  si_l[ni][d] = fs_in[n*C + d];
  #pragma unroll
  for (int x=0;x<3;x++) vi_l[ni][x][d] = fv_in[(n*C + d)*3 + x];
  __syncthreads();
  const unsigned* wrp_p = wrp + (size_t)sp*C*C;
  float bs=0, bv0=0, bv1=0, bv2=0, rs=0, rv0=0, rv1=0, rv2=0;
  #pragma unroll 4
  for (int c=0;c<C;++c){
    unsigned ud = wdp_l[c*C+d];
    unsigned ur = wrp_p[c*C+d];
    float wds = unplo(ud), wdv = unphi(ud);
    float wrs = unplo(ur), wrv = unphi(ur);
    bs  += as_l[ni][c]*wds;
    bv0 += av_l[ni][0][c]*wdv; bv1 += av_l[ni][1][c]*wdv; bv2 += av_l[ni][2][c]*wdv;
    rs  += si_l[ni][c]*wrs;
    rv0 += vi_l[ni][0][c]*wrv; rv1 += vi_l[ni][1][c]*wrv; rv2 += vi_l[ni][2][c]*wrv;
  }
  float vv = bv0*bv0 + bv1*bv1 + bv2*bv2;
  float ps  = w1s[sp*C+d]*bs + w2ss[sp*C+d]*bs*bs + w2vv[sp*C+d]*vv;
  float c1v = w1v[sp*C+d], c2sv = w2sv[sp*C+d];
  float pv0 = c1v*bv0 + c2sv*bs*bv0;
  float pv1 = c1v*bv1 + c2sv*bs*bv1;
  float pv2 = c1v*bv2 + c2sv*bs*bv2;
  __syncthreads();
  as_l[ni][d] = ps; av_l[ni][0][d]=pv0; av_l[ni][1][d]=pv1; av_l[ni][2][d]=pv2;
  __syncthreads();
  float qs=0, qv0=0, qv1=0, qv2=0;
  #pragma unroll 4
  for (int c=0;c<C;++c){
    unsigned up = wpp_l[c*C+d];
    float wps = unplo(up), wpv = unphi(up);
    qs  += as_l[ni][c]*wps;
    qv0 += av_l[ni][0][c]*wpv; qv1 += av_l[ni][1][c]*wpv; qv2 += av_l[ni][2][c]*wpv;
  }
  float fsv = qs * phi_f(fabsf(qs)) + rs;
  float nv = sqrtf(qv0*qv0 + qv1*qv1 + qv2*qv2);
  float ph = phi_f(nv);
  float fv0 = qv0*ph + rv0;
  float fv1 = qv1*ph + rv1;
  float fv2 = qv2*ph + rv2;
  out[FS_OFF + n*C + d] = fsv;
  float* fvo = &out[FV_OFF + (size_t)(n*C + d)*3];
  fvo[0]=fv0; fvo[1]=fv1; fvo[2]=fv2;
  #pragma unroll
  for (int h=0; h<HEADS; ++h){
    float r = fsv * w_read[h*C + d];
    #pragma unroll
    for (int off=32; off>0; off>>=1) r += __shfl_down(r, off);
    if (d == 0) out[n*HEADS + h] = r;
  }
}

extern "C" void kernel_launch(void* const* d_in, const int* in_sizes, int n_in,
                              void* d_out, int out_size, void* d_ws, size_t ws_size,
                              hipStream_t stream)
{
  const float* ev   = (const float*)d_in[0];
  const float* nfs  = (const float*)d_in[1];
  const float* nfv  = (const float*)d_in[2];
  const float* re   = (const float*)d_in[3];
  const int*   spec = (const int*)d_in[4];
  const int*   snd  = (const int*)d_in[5];
  const int*   rcv  = (const int*)d_in[6];
  const float* W_rs = (const float*)d_in[7];
  const float* W_rv = (const float*)d_in[8];
  const float* Wus  = (const float*)d_in[9];
  const float* Wuv  = (const float*)d_in[10];
  const float* Wr1  = (const float*)d_in[11];
  const float* Wr2  = (const float*)d_in[12];
  const float* Wds  = (const float*)d_in[13];
  const float* Wdv  = (const float*)d_in[14];
  const float* w1s  = (const float*)d_in[15];
  const float* w1v  = (const float*)d_in[16];
  const float* w2ss = (const float*)d_in[17];
  const float* w2vv = (const float*)d_in[18];
  const float* w2sv = (const float*)d_in[19];
  const float* Wps  = (const float*)d_in[20];
  const float* Wpv  = (const float*)d_in[21];
  const float* wrd  = (const float*)d_in[22];

  float* out = (float*)d_out;
  float* ws  = (float*)d_ws;
  // ws layout (f32 units)
  ushort4* suv  = (ushort4*)ws;            // 2,560,000 f32-equiv (10.24 MB)
  float*   a_sv = ws + 2560000;            // 5,120,000 (interleaved [n][c][4])
  int*    count = (int*)(ws + 7680000);    // 20,000
  int*    cursr = (int*)(ws + 7700000);    // 20,000
  int*    snd_s = (int*)(ws + 7720000);    // 320,000
  int*    rcv_s = (int*)(ws + 8040000);    // 320,000
  float4* u_s   = (float4*)(ws + 8360000); // 1,280,000 f32 (16 B/edge)
  float*  re_s  = ws + 9640000;            // 2,560,000 -> 12,200,000
  unsigned short* wr2t = (unsigned short*)(ws + 12200000);  // 10,240 f32 -> 12,210,240
  unsigned* wrp = (unsigned*)(ws + 12210240);  // 262,144 -> 12,472,384
  unsigned* wdp = (unsigned*)(ws + 12472384);  // 4,096  -> 12,476,480
  unsigned* wpp = (unsigned*)(ws + 12476480);  // 4,096  -> 12,480,576

  hipMemsetAsync(a_sv, 0, (size_t)5120000*sizeof(float), stream);
  hipMemsetAsync(count, 0, (size_t)N_NODES*sizeof(int), stream);

  prep_kernel<<<PREP_BLOCKS, 256, 0, stream>>>(
      Wr2, wr2t, W_rs, W_rv, Wds, Wdv, Wps, Wpv, wrp, wdp, wpp,
      rcv, count, nfs, nfv, Wus, Wuv, suv);
  scan_kernel<<<1, 1024, 0, stream>>>(count, cursr);
  scatter_kernel<<<E_EDGES/256, 256, 0, stream>>>(snd, rcv, ev, re, cursr,
                                                  snd_s, rcv_s, u_s, re_s);
  edge_kernel<<<NPAIR, 512, 0, stream>>>(u_s, re_s, snd_s, rcv_s, Wr1, wr2t,
                                         suv, a_sv);
  node_post_kernel<<<N_NODES/4, 256, 0, stream>>>(a_sv, nfs, nfv, spec,
      wrp, wdp, wpp, w1s, w1v, w2ss, w2vv, w2sv, wrd, out);
}

// Round 14
// 388.478 us; speedup vs baseline: 1.4371x; 1.4371x over previous
//
#include <hip/hip_runtime.h>

#define N_NODES 20000
#define C 64
#define E_EDGES 320000
#define S_SPEC 64
#define R_DIM 8
#define HR 64
#define HEADS 2
#define NPAIR (E_EDGES/128)      // 2500 blocks, 2 tiles (128 edges) each
#define HPAD 68
#define INV_AVG (1.0f/16.0f)

// fused prep grid roles
#define NB_WR2T 80
#define NB_WPACK 1056
#define NB_HIST 1250
#define NB_NODEUP 5000
#define PREP_BLOCKS (NB_WR2T + NB_WPACK + NB_HIST + NB_NODEUP)

// out layout
#define FS_OFF 40000
#define FV_OFF 1320000

typedef short bf16x4 __attribute__((ext_vector_type(4)));
typedef float f32x4  __attribute__((ext_vector_type(4)));
typedef unsigned int uint2v __attribute__((ext_vector_type(2)));
typedef float f32x4e __attribute__((ext_vector_type(4)));

__device__ __forceinline__ unsigned short f2bf(float f){
  unsigned u = __float_as_uint(f);
  u += 0x7fffu + ((u >> 16) & 1u);
  return (unsigned short)(u >> 16);
}
__device__ __forceinline__ float bf2f(unsigned short b){
  return __uint_as_float(((unsigned)b) << 16);
}
__device__ __forceinline__ unsigned packbf(float a, float b){
  return (unsigned)f2bf(a) | ((unsigned)f2bf(b) << 16);
}
__device__ __forceinline__ float unplo(unsigned u){ return __uint_as_float(u << 16); }
__device__ __forceinline__ float unphi(unsigned u){ return __uint_as_float(u & 0xffff0000u); }
__device__ __forceinline__ float phi_f(float x){
  float n = x * 0.5f;
  float s = (n > 0.0f) ? expf(-1.0f/n) : 0.0f;
  return 1.0f / (1.0f + n * s);
}

// ---------------- fused prep: wr2t | wpack | hist | node_up ---------------------------
__global__ __launch_bounds__(256) void prep_kernel(
    const float* __restrict__ Wr2, unsigned short* __restrict__ wr2t,
    const float* __restrict__ W_rs, const float* __restrict__ W_rv,
    const float* __restrict__ W_ds, const float* __restrict__ W_dv,
    const float* __restrict__ W_ps, const float* __restrict__ W_pv,
    unsigned* __restrict__ wrp, unsigned* __restrict__ wdp, unsigned* __restrict__ wpp,
    const int* __restrict__ rcv, int* __restrict__ count,
    const float* __restrict__ fs, const float* __restrict__ fv,
    const float* __restrict__ Wus, const float* __restrict__ Wuv,
    ushort4* __restrict__ suv)
{
  const int b = blockIdx.x;
  const int t = threadIdx.x;
  if (b < NB_WR2T){
    int idx = b*256 + t;
    int n = idx >> 6, k = idx & 63;
    wr2t[idx] = f2bf(Wr2[k*320 + n] * INV_AVG);
    return;
  }
  if (b < NB_WR2T + NB_WPACK){
    int idx = (b - NB_WR2T)*256 + t;
    if (idx < S_SPEC*C*C){
      wrp[idx] = packbf(W_rs[idx], W_rv[idx]);
    } else {
      int r2 = idx - S_SPEC*C*C;
      if (r2 < 4096) wdp[r2] = packbf(W_ds[r2], W_dv[r2]);
      else           wpp[r2-4096] = packbf(W_ps[r2-4096], W_pv[r2-4096]);
    }
    return;
  }
  if (b < NB_WR2T + NB_WPACK + NB_HIST){
    int e = (b - NB_WR2T - NB_WPACK)*256 + t;
    atomicAdd(&count[rcv[e]], 1);
    return;
  }
  {
    __shared__ float wus_l[C*C];
    __shared__ float wuv_l[C*C];
    __shared__ float s_l[4][C];
    __shared__ float v_l[4][3][C];
    const int nb = b - (NB_WR2T + NB_WPACK + NB_HIST);
    const int ni = t >> 6;
    const int d  = t & 63;
    const int n  = nb*4 + ni;
    #pragma unroll
    for (int j = 0; j < 16; ++j){
      wus_l[t + 256*j] = Wus[t + 256*j];
      wuv_l[t + 256*j] = Wuv[t + 256*j];
    }
    s_l[ni][d] = fs[n*C + d];
    #pragma unroll
    for (int x = 0; x < 3; ++x) v_l[ni][x][d] = fv[(n*C + d)*3 + x];
    __syncthreads();
    float as = 0.f, a0 = 0.f, a1 = 0.f, a2 = 0.f;
    #pragma unroll 4
    for (int c = 0; c < C; ++c){
      float wsv = wus_l[c*C + d];
      float wvv = wuv_l[c*C + d];
      as += s_l[ni][c] * wsv;
      a0 += v_l[ni][0][c] * wvv;
      a1 += v_l[ni][1][c] * wvv;
      a2 += v_l[ni][2][c] * wvv;
    }
    ushort4 o;
    o.x = f2bf(as); o.y = f2bf(a0); o.z = f2bf(a1); o.w = f2bf(a2);
    suv[(size_t)n*C + d] = o;
  }
}

// ---------------- scan: wave-shuffle version ------------------------------------------
__global__ __launch_bounds__(1024) void scan_kernel(const int* __restrict__ count, int* __restrict__ cursor){
  __shared__ int wsum[16];
  const int t = threadIdx.x;
  const int lane = t & 63, wid = t >> 6;
  const int base = t*20;
  int s = 0;
  int loc[20];
  #pragma unroll 4
  for (int i = 0; i < 20; ++i){
    int idx = base+i;
    int v = (idx < N_NODES) ? count[idx] : 0;
    loc[i] = v; s += v;
  }
  int x = s;
  #pragma unroll
  for (int dlt = 1; dlt < 64; dlt <<= 1){
    int y = __shfl_up(x, dlt);
    if (lane >= dlt) x += y;
  }
  if (lane == 63) wsum[wid] = x;
  __syncthreads();
  if (wid == 0 && lane < 16){
    int w = wsum[lane];
    #pragma unroll
    for (int dlt = 1; dlt < 16; dlt <<= 1){
      int y = __shfl_up(w, dlt);
      if (lane >= dlt) w += y;
    }
    wsum[lane] = w;
  }
  __syncthreads();
  int wpre = (wid > 0) ? wsum[wid-1] : 0;
  int run = wpre + (x - s);
  #pragma unroll 4
  for (int i = 0; i < 20; ++i){
    int idx = base+i;
    if (idx < N_NODES){ cursor[idx] = run; run += loc[i]; }
  }
}

// ---------------- sort pass C: scatter into sorted arrays -----------------------------
__global__ __launch_bounds__(256) void scatter_kernel(
    const int* __restrict__ snd, const int* __restrict__ rcv,
    const float* __restrict__ ev, const float* __restrict__ re,
    int* __restrict__ cursor,
    int* __restrict__ snd_s, int* __restrict__ rcv_s,
    float4* __restrict__ u_s, float* __restrict__ re_s){
  int e = blockIdx.x*256 + threadIdx.x;
  int r = rcv[e];
  int pos = atomicAdd(&cursor[r], 1);
  snd_s[pos] = snd[e];
  rcv_s[pos] = r;
  float x = ev[e*3+0], y = ev[e*3+1], z = ev[e*3+2];
  float nr = sqrtf(x*x + y*y + z*z);
  float inv = 1.0f / fmaxf(nr, 1e-9f);
  float4 u4; u4.x = x*inv; u4.y = y*inv; u4.z = z*inv; u4.w = 0.f;
  u_s[pos] = u4;
  const float4* rp = (const float4*)&re[(size_t)e*R_DIM];
  float4 ra = rp[0], rb = rp[1];
  float4* op = (float4*)&re_s[(size_t)pos*R_DIM];
  op[0] = ra; op[1] = rb;
}

// ---------------- K2: r12 edge kernel + NON-TEMPORAL streaming loads ------------------
// Separate a_s/a_v arrays (lane-major atomics, r13 lesson). nt loads keep the
// accumulator resident in L2 instead of being thrashed by the gather streams.
__global__ __launch_bounds__(512, 4) void edge_kernel(
    const float4* __restrict__ u_s, const float* __restrict__ re_s,
    const int* __restrict__ snd_s, const int* __restrict__ rcv_s,
    const float* __restrict__ Wr1, const unsigned short* __restrict__ wr2t,
    const ushort4* __restrict__ suv,
    float* __restrict__ a_s, float* __restrict__ a_v)
{
  __shared__ __align__(16) float Wr1_l[R_DIM*HR];
  __shared__ __align__(16) unsigned short Wr2T_l[320*HPAD];

  const int t = threadIdx.x;
  const int lane = t & 63;
  const int w = t >> 6;
  const int g  = w >> 1;
  const int h2 = w & 1;
  int b = blockIdx.x;
  int xcd = b & 7, idx = b >> 3;
  const int q = NPAIR >> 3, r = NPAIR & 7;
  int pair = (xcd < r ? xcd*(q+1) : r*(q+1) + (xcd-r)*q) + idx;
  const int e0A = pair * 128;
  const int e0B = e0A + 64;

  Wr1_l[t] = Wr1[t];
  #pragma unroll
  for (int j = 0; j < 10; ++j){
    int i4 = t + 512*j;
    uint2v v2 = __builtin_nontemporal_load((const uint2v*)wr2t + i4);
    int el = i4*4; int n = el >> 6, k = el & 63;
    *(uint2v*)&Wr2T_l[n*HPAD + k] = v2;
  }

  const int arow = g*16 + (lane & 15);
  const int koff = 4*(lane >> 4);
  const int cl = lane & 15;
  const int ebase = g*16 + (lane >> 4)*4;

  f32x4e raA = __builtin_nontemporal_load((const f32x4e*)&re_s[(size_t)(e0A + arow)*R_DIM]);
  f32x4e rbA = __builtin_nontemporal_load((const f32x4e*)&re_s[(size_t)(e0A + arow)*R_DIM] + 1);
  float uxA[4], uyA[4], uzA[4]; int snA[4], rcA[4];
  #pragma unroll
  for (int i = 0; i < 4; ++i){
    int e = e0A + ebase + i;
    f32x4e uu = __builtin_nontemporal_load((const f32x4e*)u_s + e);
    uxA[i]=uu.x; uyA[i]=uu.y; uzA[i]=uu.z;
    snA[i]=__builtin_nontemporal_load(snd_s + e);
    rcA[i]=__builtin_nontemporal_load(rcv_s + e);
  }
  uint2v gvA[4][2];
  #pragma unroll
  for (int i = 0; i < 4; ++i){
    const uint2v* sp_ = (const uint2v*)(suv + (size_t)snA[i]*C);
    #pragma unroll
    for (int kk = 0; kk < 2; ++kk)
      gvA[i][kk] = __builtin_nontemporal_load(sp_ + (2*h2 + kk)*16 + cl);
  }
  __syncthreads();

  bf16x4 haA[4];
  #pragma unroll
  for (int kt = 0; kt < 4; ++kt){
    short4 tmp;
    #pragma unroll
    for (int j = 0; j < 4; ++j){
      int k = kt*16 + koff + j;
      float acc = raA.x*Wr1_l[0*HR+k] + raA.y*Wr1_l[1*HR+k] + raA.z*Wr1_l[2*HR+k] + raA.w*Wr1_l[3*HR+k]
                + rbA.x*Wr1_l[4*HR+k] + rbA.y*Wr1_l[5*HR+k] + rbA.z*Wr1_l[6*HR+k] + rbA.w*Wr1_l[7*HR+k];
      float sil = acc / (1.0f + expf(-acc));
      ((unsigned short*)&tmp)[j] = f2bf(sil);
    }
    haA[kt] = *(bf16x4*)&tmp;
  }

  f32x4e raB = __builtin_nontemporal_load((const f32x4e*)&re_s[(size_t)(e0B + arow)*R_DIM]);
  f32x4e rbB = __builtin_nontemporal_load((const f32x4e*)&re_s[(size_t)(e0B + arow)*R_DIM] + 1);
  float uxB[4], uyB[4], uzB[4]; int snB[4], rcB[4];
  #pragma unroll
  for (int i = 0; i < 4; ++i){
    int e = e0B + ebase + i;
    f32x4e uu = __builtin_nontemporal_load((const f32x4e*)u_s + e);
    uxB[i]=uu.x; uyB[i]=uu.y; uzB[i]=uu.z;
    snB[i]=__builtin_nontemporal_load(snd_s + e);
    rcB[i]=__builtin_nontemporal_load(rcv_s + e);
  }

  f32x4 accA[10];
  #pragma unroll
  for (int lf = 0; lf < 10; ++lf) accA[lf] = (f32x4){0.f,0.f,0.f,0.f};
  #pragma unroll
  for (int kt = 0; kt < 4; ++kt){
    bf16x4 af = haA[kt];
    #pragma unroll
    for (int lf = 0; lf < 10; ++lf){
      int p = lf >> 1, kk = lf & 1;
      int n = (p*4 + 2*h2 + kk)*16 + cl;
      bf16x4 bf = *(const bf16x4*)&Wr2T_l[n*HPAD + kt*16 + koff];
      accA[lf] = __builtin_amdgcn_mfma_f32_16x16x16bf16_1k(af, bf, accA[lf], 0, 0, 0);
    }
  }

  uint2v gvB[4][2];
  #pragma unroll
  for (int i = 0; i < 4; ++i){
    const uint2v* sp_ = (const uint2v*)(suv + (size_t)snB[i]*C);
    #pragma unroll
    for (int kk = 0; kk < 2; ++kk)
      gvB[i][kk] = __builtin_nontemporal_load(sp_ + (2*h2 + kk)*16 + cl);
  }

  {
    float ms[2], mv0[2], mv1[2], mv2[2];
    #pragma unroll
    for (int kk = 0; kk < 2; ++kk){ ms[kk]=0.f; mv0[kk]=0.f; mv1[kk]=0.f; mv2[kk]=0.f; }
    int cur = rcA[0];
    #pragma unroll
    for (int i = 0; i < 4; ++i){
      int rc = rcA[i];
      if (rc != cur){
        #pragma unroll
        for (int kk = 0; kk < 2; ++kk){
          int c = (2*h2 + kk)*16 + cl;
          unsafeAtomicAdd(&a_s[cur*C + c],       ms[kk]);
          unsafeAtomicAdd(&a_v[(cur*3+0)*C + c], mv0[kk]);
          unsafeAtomicAdd(&a_v[(cur*3+1)*C + c], mv1[kk]);
          unsafeAtomicAdd(&a_v[(cur*3+2)*C + c], mv2[kk]);
          ms[kk]=0.f; mv0[kk]=0.f; mv1[kk]=0.f; mv2[kk]=0.f;
        }
        cur = rc;
      }
      float u0 = uxA[i], u1 = uyA[i], u2 = uzA[i];
      #pragma unroll
      for (int kk = 0; kk < 2; ++kk){
        float se  = unplo(gvA[i][kk].x);
        float ve0 = unphi(gvA[i][kk].x);
        float ve1 = unplo(gvA[i][kk].y);
        float ve2 = unphi(gvA[i][kk].y);
        float w0 = accA[0*2+kk][i];
        float w1 = accA[1*2+kk][i];
        float w2 = accA[2*2+kk][i];
        float w3 = accA[3*2+kk][i];
        float w4 = accA[4*2+kk][i];
        float dt  = ve0*u0 + ve1*u1 + ve2*u2;
        float cr0 = ve1*u2 - ve2*u1;
        float cr1 = ve2*u0 - ve0*u2;
        float cr2 = ve0*u1 - ve1*u0;
        ms[kk]  += w0*se + w3*dt;
        mv0[kk] += w1*ve0 + w2*u0 + w4*cr0;
        mv1[kk] += w1*ve1 + w2*u1 + w4*cr1;
        mv2[kk] += w1*ve2 + w2*u2 + w4*cr2;
      }
    }
    #pragma unroll
    for (int kk = 0; kk < 2; ++kk){
      int c = (2*h2 + kk)*16 + cl;
      unsafeAtomicAdd(&a_s[cur*C + c],       ms[kk]);
      unsafeAtomicAdd(&a_v[(cur*3+0)*C + c], mv0[kk]);
      unsafeAtomicAdd(&a_v[(cur*3+1)*C + c], mv1[kk]);
      unsafeAtomicAdd(&a_v[(cur*3+2)*C + c], mv2[kk]);
    }
  }

  bf16x4 haB[4];
  #pragma unroll
  for (int kt = 0; kt < 4; ++kt){
    short4 tmp;
    #pragma unroll
    for (int j = 0; j < 4; ++j){
      int k = kt*16 + koff + j;
      float acc = raB.x*Wr1_l[0*HR+k] + raB.y*Wr1_l[1*HR+k] + raB.z*Wr1_l[2*HR+k] + raB.w*Wr1_l[3*HR+k]
                + rbB.x*Wr1_l[4*HR+k] + rbB.y*Wr1_l[5*HR+k] + rbB.z*Wr1_l[6*HR+k] + rbB.w*Wr1_l[7*HR+k];
      float sil = acc / (1.0f + expf(-acc));
      ((unsigned short*)&tmp)[j] = f2bf(sil);
    }
    haB[kt] = *(bf16x4*)&tmp;
  }
  f32x4 accB[10];
  #pragma unroll
  for (int lf = 0; lf < 10; ++lf) accB[lf] = (f32x4){0.f,0.f,0.f,0.f};
  #pragma unroll
  for (int kt = 0; kt < 4; ++kt){
    bf16x4 af = haB[kt];
    #pragma unroll
    for (int lf = 0; lf < 10; ++lf){
      int p = lf >> 1, kk = lf & 1;
      int n = (p*4 + 2*h2 + kk)*16 + cl;
      bf16x4 bf = *(const bf16x4*)&Wr2T_l[n*HPAD + kt*16 + koff];
      accB[lf] = __builtin_amdgcn_mfma_f32_16x16x16bf16_1k(af, bf, accB[lf], 0, 0, 0);
    }
  }

  {
    float ms[2], mv0[2], mv1[2], mv2[2];
    #pragma unroll
    for (int kk = 0; kk < 2; ++kk){ ms[kk]=0.f; mv0[kk]=0.f; mv1[kk]=0.f; mv2[kk]=0.f; }
    int cur = rcB[0];
    #pragma unroll
    for (int i = 0; i < 4; ++i){
      int rc = rcB[i];
      if (rc != cur){
        #pragma unroll
        for (int kk = 0; kk < 2; ++kk){
          int c = (2*h2 + kk)*16 + cl;
          unsafeAtomicAdd(&a_s[cur*C + c],       ms[kk]);
          unsafeAtomicAdd(&a_v[(cur*3+0)*C + c], mv0[kk]);
          unsafeAtomicAdd(&a_v[(cur*3+1)*C + c], mv1[kk]);
          unsafeAtomicAdd(&a_v[(cur*3+2)*C + c], mv2[kk]);
          ms[kk]=0.f; mv0[kk]=0.f; mv1[kk]=0.f; mv2[kk]=0.f;
        }
        cur = rc;
      }
      float u0 = uxB[i], u1 = uyB[i], u2 = uzB[i];
      #pragma unroll
      for (int kk = 0; kk < 2; ++kk){
        float se  = unplo(gvB[i][kk].x);
        float ve0 = unphi(gvB[i][kk].x);
        float ve1 = unplo(gvB[i][kk].y);
        float ve2 = unphi(gvB[i][kk].y);
        float w0 = accB[0*2+kk][i];
        float w1 = accB[1*2+kk][i];
        float w2 = accB[2*2+kk][i];
        float w3 = accB[3*2+kk][i];
        float w4 = accB[4*2+kk][i];
        float dt  = ve0*u0 + ve1*u1 + ve2*u2;
        float cr0 = ve1*u2 - ve2*u1;
        float cr1 = ve2*u0 - ve0*u2;
        float cr2 = ve0*u1 - ve1*u0;
        ms[kk]  += w0*se + w3*dt;
        mv0[kk] += w1*ve0 + w2*u0 + w4*cr0;
        mv1[kk] += w1*ve1 + w2*u1 + w4*cr1;
        mv2[kk] += w1*ve2 + w2*u2 + w4*cr2;
      }
    }
    #pragma unroll
    for (int kk = 0; kk < 2; ++kk){
      int c = (2*h2 + kk)*16 + cl;
      unsafeAtomicAdd(&a_s[cur*C + c],       ms[kk]);
      unsafeAtomicAdd(&a_v[(cur*3+0)*C + c], mv0[kk]);
      unsafeAtomicAdd(&a_v[(cur*3+1)*C + c], mv1[kk]);
      unsafeAtomicAdd(&a_v[(cur*3+2)*C + c], mv2[kk]);
    }
  }
}

// ---------------- K3: node_post with LDS packed weights (r12 form) --------------------
__global__ __launch_bounds__(256) void node_post_kernel(
    const float* __restrict__ a_s, const float* __restrict__ a_v,
    const float* __restrict__ fs_in, const float* __restrict__ fv_in,
    const int* __restrict__ species,
    const unsigned* __restrict__ wrp,
    const unsigned* __restrict__ wdp,
    const unsigned* __restrict__ wpp,
    const float* __restrict__ w1s, const float* __restrict__ w1v,
    const float* __restrict__ w2ss, const float* __restrict__ w2vv, const float* __restrict__ w2sv,
    const float* __restrict__ w_read, float* __restrict__ out)
{
  const int ni = threadIdx.x >> 6;
  const int d  = threadIdx.x & 63;
  const int n  = blockIdx.x*4 + ni;
  const int sp = species[n];
  const int t  = threadIdx.x;
  __shared__ float as_l[4][C];
  __shared__ float av_l[4][3][C];
  __shared__ float si_l[4][C];
  __shared__ float vi_l[4][3][C];
  __shared__ unsigned wdp_l[C*C];
  __shared__ unsigned wpp_l[C*C];
  #pragma unroll
  for (int j = 0; j < 16; ++j){
    wdp_l[t + 256*j] = wdp[t + 256*j];
    wpp_l[t + 256*j] = wpp[t + 256*j];
  }
  as_l[ni][d] = a_s[n*C + d];
  #pragma unroll
  for (int x=0;x<3;x++) av_l[ni][x][d] = a_v[(n*3+x)*C + d];
  si_l[ni][d] = fs_in[n*C + d];
  #pragma unroll
  for (int x=0;x<3;x++) vi_l[ni][x][d] = fv_in[(n*C + d)*3 + x];
  __syncthreads();
  const unsigned* wrp_p = wrp + (size_t)sp*C*C;
  float bs=0, bv0=0, bv1=0, bv2=0, rs=0, rv0=0, rv1=0, rv2=0;
  #pragma unroll 4
  for (int c=0;c<C;++c){
    unsigned ud = wdp_l[c*C+d];
    unsigned ur = wrp_p[c*C+d];
    float wds = unplo(ud), wdv = unphi(ud);
    float wrs = unplo(ur), wrv = unphi(ur);
    bs  += as_l[ni][c]*wds;
    bv0 += av_l[ni][0][c]*wdv; bv1 += av_l[ni][1][c]*wdv; bv2 += av_l[ni][2][c]*wdv;
    rs  += si_l[ni][c]*wrs;
    rv0 += vi_l[ni][0][c]*wrv; rv1 += vi_l[ni][1][c]*wrv; rv2 += vi_l[ni][2][c]*wrv;
  }
  float vv = bv0*bv0 + bv1*bv1 + bv2*bv2;
  float ps  = w1s[sp*C+d]*bs + w2ss[sp*C+d]*bs*bs + w2vv[sp*C+d]*vv;
  float c1v = w1v[sp*C+d], c2sv = w2sv[sp*C+d];
  float pv0 = c1v*bv0 + c2sv*bs*bv0;
  float pv1 = c1v*bv1 + c2sv*bs*bv1;
  float pv2 = c1v*bv2 + c2sv*bs*bv2;
  __syncthreads();
  as_l[ni][d] = ps; av_l[ni][0][d]=pv0; av_l[ni][1][d]=pv1; av_l[ni][2][d]=pv2;
  __syncthreads();
  float qs=0, qv0=0, qv1=0, qv2=0;
  #pragma unroll 4
  for (int c=0;c<C;++c){
    unsigned up = wpp_l[c*C+d];
    float wps = unplo(up), wpv = unphi(up);
    qs  += as_l[ni][c]*wps;
    qv0 += av_l[ni][0][c]*wpv; qv1 += av_l[ni][1][c]*wpv; qv2 += av_l[ni][2][c]*wpv;
  }
  float fsv = qs * phi_f(fabsf(qs)) + rs;
  float nv = sqrtf(qv0*qv0 + qv1*qv1 + qv2*qv2);
  float ph = phi_f(nv);
  float fv0 = qv0*ph + rv0;
  float fv1 = qv1*ph + rv1;
  float fv2 = qv2*ph + rv2;
  out[FS_OFF + n*C + d] = fsv;
  float* fvo = &out[FV_OFF + (size_t)(n*C + d)*3];
  fvo[0]=fv0; fvo[1]=fv1; fvo[2]=fv2;
  #pragma unroll
  for (int h=0; h<HEADS; ++h){
    float r = fsv * w_read[h*C + d];
    #pragma unroll
    for (int off=32; off>0; off>>=1) r += __shfl_down(r, off);
    if (d == 0) out[n*HEADS + h] = r;
  }
}

extern "C" void kernel_launch(void* const* d_in, const int* in_sizes, int n_in,
                              void* d_out, int out_size, void* d_ws, size_t ws_size,
                              hipStream_t stream)
{
  const float* ev   = (const float*)d_in[0];
  const float* nfs  = (const float*)d_in[1];
  const float* nfv  = (const float*)d_in[2];
  const float* re   = (const float*)d_in[3];
  const int*   spec = (const int*)d_in[4];
  const int*   snd  = (const int*)d_in[5];
  const int*   rcv  = (const int*)d_in[6];
  const float* W_rs = (const float*)d_in[7];
  const float* W_rv = (const float*)d_in[8];
  const float* Wus  = (const float*)d_in[9];
  const float* Wuv  = (const float*)d_in[10];
  const float* Wr1  = (const float*)d_in[11];
  const float* Wr2  = (const float*)d_in[12];
  const float* Wds  = (const float*)d_in[13];
  const float* Wdv  = (const float*)d_in[14];
  const float* w1s  = (const float*)d_in[15];
  const float* w1v  = (const float*)d_in[16];
  const float* w2ss = (const float*)d_in[17];
  const float* w2vv = (const float*)d_in[18];
  const float* w2sv = (const float*)d_in[19];
  const float* Wps  = (const float*)d_in[20];
  const float* Wpv  = (const float*)d_in[21];
  const float* wrd  = (const float*)d_in[22];

  float* out = (float*)d_out;
  float* ws  = (float*)d_ws;
  // ws layout (f32 units) — r12 proven layout
  ushort4* suv  = (ushort4*)ws;            // 2,560,000
  float*   a_s  = ws + 2560000;            // 1,280,000
  float*   a_v  = ws + 3840000;            // 3,840,000
  int*    count = (int*)(ws + 7680000);    // 20,000
  int*    cursr = (int*)(ws + 7700000);    // 20,000
  int*    snd_s = (int*)(ws + 7720000);    // 320,000
  int*    rcv_s = (int*)(ws + 8040000);    // 320,000
  float4* u_s   = (float4*)(ws + 8360000); // 1,280,000
  float*  re_s  = ws + 9640000;            // 2,560,000 -> 12,200,000
  unsigned short* wr2t = (unsigned short*)(ws + 12200000);  // -> 12,210,240
  unsigned* wrp = (unsigned*)(ws + 12210240);  // 262,144 -> 12,472,384
  unsigned* wdp = (unsigned*)(ws + 12472384);  // 4,096
  unsigned* wpp = (unsigned*)(ws + 12476480);  // 4,096 -> 12,480,576

  hipMemsetAsync(a_s, 0, (size_t)5120000*sizeof(float), stream);   // a_s + a_v
  hipMemsetAsync(count, 0, (size_t)N_NODES*sizeof(int), stream);

  prep_kernel<<<PREP_BLOCKS, 256, 0, stream>>>(
      Wr2, wr2t, W_rs, W_rv, Wds, Wdv, Wps, Wpv, wrp, wdp, wpp,
      rcv, count, nfs, nfv, Wus, Wuv, suv);
  scan_kernel<<<1, 1024, 0, stream>>>(count, cursr);
  scatter_kernel<<<E_EDGES/256, 256, 0, stream>>>(snd, rcv, ev, re, cursr,
                                                  snd_s, rcv_s, u_s, re_s);
  edge_kernel<<<NPAIR, 512, 0, stream>>>(u_s, re_s, snd_s, rcv_s, Wr1, wr2t,
                                         suv, a_s, a_v);
  node_post_kernel<<<N_NODES/4, 256, 0, stream>>>(a_s, a_v, nfs, nfv, spec,
      wrp, wdp, wpp, w1s, w1v, w2ss, w2vv, w2sv, wrd, out);
}

// Round 15
// 378.708 us; speedup vs baseline: 1.4742x; 1.0258x over previous
//
#include <hip/hip_runtime.h>

#define N_NODES 20000
#define C 64
#define E_EDGES 320000
#define S_SPEC 64
#define R_DIM 8
#define HR 64
#define HEADS 2
#define NPAIR (E_EDGES/128)      // 2500 blocks, 2 tiles (128 edges) each
#define HPAD 68
#define INV_AVG (1.0f/16.0f)

// fused prep grid roles
#define NB_WR2T 80
#define NB_WPACK 1056
#define NB_HIST 1250
#define NB_NODEUP 2500           // 8 nodes/block, 2 passes of 4
#define PREP_BLOCKS (NB_WR2T + NB_WPACK + NB_HIST + NB_NODEUP)

// out layout
#define FS_OFF 40000
#define FV_OFF 1320000

typedef short bf16x4 __attribute__((ext_vector_type(4)));
typedef float f32x4  __attribute__((ext_vector_type(4)));

__device__ __forceinline__ unsigned short f2bf(float f){
  unsigned u = __float_as_uint(f);
  u += 0x7fffu + ((u >> 16) & 1u);
  return (unsigned short)(u >> 16);
}
__device__ __forceinline__ float bf2f(unsigned short b){
  return __uint_as_float(((unsigned)b) << 16);
}
__device__ __forceinline__ unsigned packbf(float a, float b){
  return (unsigned)f2bf(a) | ((unsigned)f2bf(b) << 16);
}
__device__ __forceinline__ float unplo(unsigned u){ return __uint_as_float(u << 16); }
__device__ __forceinline__ float unphi(unsigned u){ return __uint_as_float(u & 0xffff0000u); }
__device__ __forceinline__ float phi_f(float x){
  float n = x * 0.5f;
  float s = (n > 0.0f) ? expf(-1.0f/n) : 0.0f;
  return 1.0f / (1.0f + n * s);
}

// ---------------- fused prep: wr2t | wpack | hist | node_up (8 nodes/block) -----------
__global__ __launch_bounds__(256) void prep_kernel(
    const float* __restrict__ Wr2, unsigned short* __restrict__ wr2t,
    const float* __restrict__ W_rs, const float* __restrict__ W_rv,
    const float* __restrict__ W_ds, const float* __restrict__ W_dv,
    const float* __restrict__ W_ps, const float* __restrict__ W_pv,
    unsigned* __restrict__ wrp, unsigned* __restrict__ wdp, unsigned* __restrict__ wpp,
    const int* __restrict__ rcv, int* __restrict__ count,
    const float* __restrict__ fs, const float* __restrict__ fv,
    const float* __restrict__ Wus, const float* __restrict__ Wuv,
    ushort4* __restrict__ suv)
{
  const int b = blockIdx.x;
  const int t = threadIdx.x;
  if (b < NB_WR2T){
    int idx = b*256 + t;
    int n = idx >> 6, k = idx & 63;
    wr2t[idx] = f2bf(Wr2[k*320 + n] * INV_AVG);
    return;
  }
  if (b < NB_WR2T + NB_WPACK){
    int idx = (b - NB_WR2T)*256 + t;
    if (idx < S_SPEC*C*C){
      wrp[idx] = packbf(W_rs[idx], W_rv[idx]);
    } else {
      int r2 = idx - S_SPEC*C*C;
      if (r2 < 4096) wdp[r2] = packbf(W_ds[r2], W_dv[r2]);
      else           wpp[r2-4096] = packbf(W_ps[r2-4096], W_pv[r2-4096]);
    }
    return;
  }
  if (b < NB_WR2T + NB_WPACK + NB_HIST){
    int e = (b - NB_WR2T - NB_WPACK)*256 + t;
    atomicAdd(&count[rcv[e]], 1);
    return;
  }
  // node_up role: 8 nodes/block (2 passes of 4), weights staged once
  {
    __shared__ float wus_l[C*C];    // 16 KB
    __shared__ float wuv_l[C*C];    // 16 KB
    __shared__ float s_l[4][C];
    __shared__ float v_l[4][3][C];
    const int nb = b - (NB_WR2T + NB_WPACK + NB_HIST);
    const int ni = t >> 6;
    const int d  = t & 63;
    #pragma unroll
    for (int j = 0; j < 16; ++j){
      wus_l[t + 256*j] = Wus[t + 256*j];
      wuv_l[t + 256*j] = Wuv[t + 256*j];
    }
    #pragma unroll
    for (int pass = 0; pass < 2; ++pass){
      const int n = nb*8 + pass*4 + ni;
      s_l[ni][d] = fs[n*C + d];
      #pragma unroll
      for (int x = 0; x < 3; ++x) v_l[ni][x][d] = fv[(n*C + d)*3 + x];
      __syncthreads();
      float as = 0.f, a0 = 0.f, a1 = 0.f, a2 = 0.f;
      #pragma unroll 4
      for (int c = 0; c < C; ++c){
        float wsv = wus_l[c*C + d];
        float wvv = wuv_l[c*C + d];
        as += s_l[ni][c] * wsv;
        a0 += v_l[ni][0][c] * wvv;
        a1 += v_l[ni][1][c] * wvv;
        a2 += v_l[ni][2][c] * wvv;
      }
      ushort4 o;
      o.x = f2bf(as); o.y = f2bf(a0); o.z = f2bf(a1); o.w = f2bf(a2);
      suv[(size_t)n*C + d] = o;
      __syncthreads();
    }
  }
}

// ---------------- scan: wave-shuffle version ------------------------------------------
__global__ __launch_bounds__(1024) void scan_kernel(const int* __restrict__ count, int* __restrict__ cursor){
  __shared__ int wsum[16];
  const int t = threadIdx.x;
  const int lane = t & 63, wid = t >> 6;
  const int base = t*20;
  int s = 0;
  int loc[20];
  #pragma unroll 4
  for (int i = 0; i < 20; ++i){
    int idx = base+i;
    int v = (idx < N_NODES) ? count[idx] : 0;
    loc[i] = v; s += v;
  }
  int x = s;
  #pragma unroll
  for (int dlt = 1; dlt < 64; dlt <<= 1){
    int y = __shfl_up(x, dlt);
    if (lane >= dlt) x += y;
  }
  if (lane == 63) wsum[wid] = x;
  __syncthreads();
  if (wid == 0 && lane < 16){
    int w = wsum[lane];
    #pragma unroll
    for (int dlt = 1; dlt < 16; dlt <<= 1){
      int y = __shfl_up(w, dlt);
      if (lane >= dlt) w += y;
    }
    wsum[lane] = w;
  }
  __syncthreads();
  int wpre = (wid > 0) ? wsum[wid-1] : 0;
  int run = wpre + (x - s);
  #pragma unroll 4
  for (int i = 0; i < 20; ++i){
    int idx = base+i;
    if (idx < N_NODES){ cursor[idx] = run; run += loc[i]; }
  }
}

// ---------------- sort pass C: scatter into sorted arrays -----------------------------
__global__ __launch_bounds__(256) void scatter_kernel(
    const int* __restrict__ snd, const int* __restrict__ rcv,
    const float* __restrict__ ev, const float* __restrict__ re,
    int* __restrict__ cursor,
    int* __restrict__ snd_s, int* __restrict__ rcv_s,
    float4* __restrict__ u_s, float* __restrict__ re_s){
  int e = blockIdx.x*256 + threadIdx.x;
  int r = rcv[e];
  int pos = atomicAdd(&cursor[r], 1);
  snd_s[pos] = snd[e];
  rcv_s[pos] = r;
  float x = ev[e*3+0], y = ev[e*3+1], z = ev[e*3+2];
  float nr = sqrtf(x*x + y*y + z*z);
  float inv = 1.0f / fmaxf(nr, 1e-9f);
  float4 u4; u4.x = x*inv; u4.y = y*inv; u4.z = z*inv; u4.w = 0.f;
  u_s[pos] = u4;
  const float4* rp = (const float4*)&re[(size_t)e*R_DIM];
  float4 ra = rp[0], rb = rp[1];
  float4* op = (float4*)&re_s[(size_t)pos*R_DIM];
  op[0] = ra; op[1] = rb;
}

// ---------------- K2: MFMA radial GEMM, 2-tile pipeline (r12 body, frozen) ------------
__global__ __launch_bounds__(512, 4) void edge_kernel(
    const float4* __restrict__ u_s, const float* __restrict__ re_s,
    const int* __restrict__ snd_s, const int* __restrict__ rcv_s,
    const float* __restrict__ Wr1, const unsigned short* __restrict__ wr2t,
    const ushort4* __restrict__ suv,
    float* __restrict__ a_s, float* __restrict__ a_v)
{
  __shared__ __align__(16) float Wr1_l[R_DIM*HR];
  __shared__ __align__(16) unsigned short Wr2T_l[320*HPAD];

  const int t = threadIdx.x;
  const int lane = t & 63;
  const int w = t >> 6;
  const int g  = w >> 1;
  const int h2 = w & 1;
  int b = blockIdx.x;
  int xcd = b & 7, idx = b >> 3;
  const int q = NPAIR >> 3, r = NPAIR & 7;
  int pair = (xcd < r ? xcd*(q+1) : r*(q+1) + (xcd-r)*q) + idx;
  const int e0A = pair * 128;
  const int e0B = e0A + 64;

  Wr1_l[t] = Wr1[t];
  #pragma unroll
  for (int j = 0; j < 10; ++j){
    int i4 = t + 512*j;
    ushort4 v4 = ((const ushort4*)wr2t)[i4];
    int el = i4*4; int n = el >> 6, k = el & 63;
    *(ushort4*)&Wr2T_l[n*HPAD + k] = v4;
  }

  const int arow = g*16 + (lane & 15);
  const int koff = 4*(lane >> 4);
  const int cl = lane & 15;
  const int ebase = g*16 + (lane >> 4)*4;

  float4 raA = ((const float4*)&re_s[(size_t)(e0A + arow)*R_DIM])[0];
  float4 rbA = ((const float4*)&re_s[(size_t)(e0A + arow)*R_DIM])[1];
  float uxA[4], uyA[4], uzA[4]; int snA[4], rcA[4];
  #pragma unroll
  for (int i = 0; i < 4; ++i){
    int e = e0A + ebase + i;
    float4 uu = u_s[e];
    uxA[i]=uu.x; uyA[i]=uu.y; uzA[i]=uu.z;
    snA[i]=snd_s[e]; rcA[i]=rcv_s[e];
  }
  ushort4 gvA[4][2];
  #pragma unroll
  for (int i = 0; i < 4; ++i){
    const ushort4* sp_ = &suv[(size_t)snA[i]*C];
    #pragma unroll
    for (int kk = 0; kk < 2; ++kk) gvA[i][kk] = sp_[(2*h2 + kk)*16 + cl];
  }
  __syncthreads();

  bf16x4 haA[4];
  #pragma unroll
  for (int kt = 0; kt < 4; ++kt){
    short4 tmp;
    #pragma unroll
    for (int j = 0; j < 4; ++j){
      int k = kt*16 + koff + j;
      float acc = raA.x*Wr1_l[0*HR+k] + raA.y*Wr1_l[1*HR+k] + raA.z*Wr1_l[2*HR+k] + raA.w*Wr1_l[3*HR+k]
                + rbA.x*Wr1_l[4*HR+k] + rbA.y*Wr1_l[5*HR+k] + rbA.z*Wr1_l[6*HR+k] + rbA.w*Wr1_l[7*HR+k];
      float sil = acc / (1.0f + expf(-acc));
      ((unsigned short*)&tmp)[j] = f2bf(sil);
    }
    haA[kt] = *(bf16x4*)&tmp;
  }

  float4 raB = ((const float4*)&re_s[(size_t)(e0B + arow)*R_DIM])[0];
  float4 rbB = ((const float4*)&re_s[(size_t)(e0B + arow)*R_DIM])[1];
  float uxB[4], uyB[4], uzB[4]; int snB[4], rcB[4];
  #pragma unroll
  for (int i = 0; i < 4; ++i){
    int e = e0B + ebase + i;
    float4 uu = u_s[e];
    uxB[i]=uu.x; uyB[i]=uu.y; uzB[i]=uu.z;
    snB[i]=snd_s[e]; rcB[i]=rcv_s[e];
  }

  f32x4 accA[10];
  #pragma unroll
  for (int lf = 0; lf < 10; ++lf) accA[lf] = (f32x4){0.f,0.f,0.f,0.f};
  #pragma unroll
  for (int kt = 0; kt < 4; ++kt){
    bf16x4 af = haA[kt];
    #pragma unroll
    for (int lf = 0; lf < 10; ++lf){
      int p = lf >> 1, kk = lf & 1;
      int n = (p*4 + 2*h2 + kk)*16 + cl;
      bf16x4 bf = *(const bf16x4*)&Wr2T_l[n*HPAD + kt*16 + koff];
      accA[lf] = __builtin_amdgcn_mfma_f32_16x16x16bf16_1k(af, bf, accA[lf], 0, 0, 0);
    }
  }

  ushort4 gvB[4][2];
  #pragma unroll
  for (int i = 0; i < 4; ++i){
    const ushort4* sp_ = &suv[(size_t)snB[i]*C];
    #pragma unroll
    for (int kk = 0; kk < 2; ++kk) gvB[i][kk] = sp_[(2*h2 + kk)*16 + cl];
  }

  {
    float ms[2], mv0[2], mv1[2], mv2[2];
    #pragma unroll
    for (int kk = 0; kk < 2; ++kk){ ms[kk]=0.f; mv0[kk]=0.f; mv1[kk]=0.f; mv2[kk]=0.f; }
    int cur = rcA[0];
    #pragma unroll
    for (int i = 0; i < 4; ++i){
      int rc = rcA[i];
      if (rc != cur){
        #pragma unroll
        for (int kk = 0; kk < 2; ++kk){
          int c = (2*h2 + kk)*16 + cl;
          unsafeAtomicAdd(&a_s[cur*C + c],       ms[kk]);
          unsafeAtomicAdd(&a_v[(cur*3+0)*C + c], mv0[kk]);
          unsafeAtomicAdd(&a_v[(cur*3+1)*C + c], mv1[kk]);
          unsafeAtomicAdd(&a_v[(cur*3+2)*C + c], mv2[kk]);
          ms[kk]=0.f; mv0[kk]=0.f; mv1[kk]=0.f; mv2[kk]=0.f;
        }
        cur = rc;
      }
      float u0 = uxA[i], u1 = uyA[i], u2 = uzA[i];
      #pragma unroll
      for (int kk = 0; kk < 2; ++kk){
        float se  = bf2f(gvA[i][kk].x);
        float ve0 = bf2f(gvA[i][kk].y);
        float ve1 = bf2f(gvA[i][kk].z);
        float ve2 = bf2f(gvA[i][kk].w);
        float w0 = accA[0*2+kk][i];
        float w1 = accA[1*2+kk][i];
        float w2 = accA[2*2+kk][i];
        float w3 = accA[3*2+kk][i];
        float w4 = accA[4*2+kk][i];
        float dt  = ve0*u0 + ve1*u1 + ve2*u2;
        float cr0 = ve1*u2 - ve2*u1;
        float cr1 = ve2*u0 - ve0*u2;
        float cr2 = ve0*u1 - ve1*u0;
        ms[kk]  += w0*se + w3*dt;
        mv0[kk] += w1*ve0 + w2*u0 + w4*cr0;
        mv1[kk] += w1*ve1 + w2*u1 + w4*cr1;
        mv2[kk] += w1*ve2 + w2*u2 + w4*cr2;
      }
    }
    #pragma unroll
    for (int kk = 0; kk < 2; ++kk){
      int c = (2*h2 + kk)*16 + cl;
      unsafeAtomicAdd(&a_s[cur*C + c],       ms[kk]);
      unsafeAtomicAdd(&a_v[(cur*3+0)*C + c], mv0[kk]);
      unsafeAtomicAdd(&a_v[(cur*3+1)*C + c], mv1[kk]);
      unsafeAtomicAdd(&a_v[(cur*3+2)*C + c], mv2[kk]);
    }
  }

  bf16x4 haB[4];
  #pragma unroll
  for (int kt = 0; kt < 4; ++kt){
    short4 tmp;
    #pragma unroll
    for (int j = 0; j < 4; ++j){
      int k = kt*16 + koff + j;
      float acc = raB.x*Wr1_l[0*HR+k] + raB.y*Wr1_l[1*HR+k] + raB.z*Wr1_l[2*HR+k] + raB.w*Wr1_l[3*HR+k]
                + rbB.x*Wr1_l[4*HR+k] + rbB.y*Wr1_l[5*HR+k] + rbB.z*Wr1_l[6*HR+k] + rbB.w*Wr1_l[7*HR+k];
      float sil = acc / (1.0f + expf(-acc));
      ((unsigned short*)&tmp)[j] = f2bf(sil);
    }
    haB[kt] = *(bf16x4*)&tmp;
  }
  f32x4 accB[10];
  #pragma unroll
  for (int lf = 0; lf < 10; ++lf) accB[lf] = (f32x4){0.f,0.f,0.f,0.f};
  #pragma unroll
  for (int kt = 0; kt < 4; ++kt){
    bf16x4 af = haB[kt];
    #pragma unroll
    for (int lf = 0; lf < 10; ++lf){
      int p = lf >> 1, kk = lf & 1;
      int n = (p*4 + 2*h2 + kk)*16 + cl;
      bf16x4 bf = *(const bf16x4*)&Wr2T_l[n*HPAD + kt*16 + koff];
      accB[lf] = __builtin_amdgcn_mfma_f32_16x16x16bf16_1k(af, bf, accB[lf], 0, 0, 0);
    }
  }

  {
    float ms[2], mv0[2], mv1[2], mv2[2];
    #pragma unroll
    for (int kk = 0; kk < 2; ++kk){ ms[kk]=0.f; mv0[kk]=0.f; mv1[kk]=0.f; mv2[kk]=0.f; }
    int cur = rcB[0];
    #pragma unroll
    for (int i = 0; i < 4; ++i){
      int rc = rcB[i];
      if (rc != cur){
        #pragma unroll
        for (int kk = 0; kk < 2; ++kk){
          int c = (2*h2 + kk)*16 + cl;
          unsafeAtomicAdd(&a_s[cur*C + c],       ms[kk]);
          unsafeAtomicAdd(&a_v[(cur*3+0)*C + c], mv0[kk]);
          unsafeAtomicAdd(&a_v[(cur*3+1)*C + c], mv1[kk]);
          unsafeAtomicAdd(&a_v[(cur*3+2)*C + c], mv2[kk]);
          ms[kk]=0.f; mv0[kk]=0.f; mv1[kk]=0.f; mv2[kk]=0.f;
        }
        cur = rc;
      }
      float u0 = uxB[i], u1 = uyB[i], u2 = uzB[i];
      #pragma unroll
      for (int kk = 0; kk < 2; ++kk){
        float se  = bf2f(gvB[i][kk].x);
        float ve0 = bf2f(gvB[i][kk].y);
        float ve1 = bf2f(gvB[i][kk].z);
        float ve2 = bf2f(gvB[i][kk].w);
        float w0 = accB[0*2+kk][i];
        float w1 = accB[1*2+kk][i];
        float w2 = accB[2*2+kk][i];
        float w3 = accB[3*2+kk][i];
        float w4 = accB[4*2+kk][i];
        float dt  = ve0*u0 + ve1*u1 + ve2*u2;
        float cr0 = ve1*u2 - ve2*u1;
        float cr1 = ve2*u0 - ve0*u2;
        float cr2 = ve0*u1 - ve1*u0;
        ms[kk]  += w0*se + w3*dt;
        mv0[kk] += w1*ve0 + w2*u0 + w4*cr0;
        mv1[kk] += w1*ve1 + w2*u1 + w4*cr1;
        mv2[kk] += w1*ve2 + w2*u2 + w4*cr2;
      }
    }
    #pragma unroll
    for (int kk = 0; kk < 2; ++kk){
      int c = (2*h2 + kk)*16 + cl;
      unsafeAtomicAdd(&a_s[cur*C + c],       ms[kk]);
      unsafeAtomicAdd(&a_v[(cur*3+0)*C + c], mv0[kk]);
      unsafeAtomicAdd(&a_v[(cur*3+1)*C + c], mv1[kk]);
      unsafeAtomicAdd(&a_v[(cur*3+2)*C + c], mv2[kk]);
    }
  }
}

// ---------------- K3: node_post, 512 threads / 8 nodes per block ----------------------
__global__ __launch_bounds__(512) void node_post_kernel(
    const float* __restrict__ a_s, const float* __restrict__ a_v,
    const float* __restrict__ fs_in, const float* __restrict__ fv_in,
    const int* __restrict__ species,
    const unsigned* __restrict__ wrp,
    const unsigned* __restrict__ wdp,
    const unsigned* __restrict__ wpp,
    const float* __restrict__ w1s, const float* __restrict__ w1v,
    const float* __restrict__ w2ss, const float* __restrict__ w2vv, const float* __restrict__ w2sv,
    const float* __restrict__ w_read, float* __restrict__ out)
{
  const int ni = threadIdx.x >> 6;   // 0..7
  const int d  = threadIdx.x & 63;
  const int n  = blockIdx.x*8 + ni;
  const int sp = species[n];
  const int t  = threadIdx.x;
  __shared__ float as_l[8][C];
  __shared__ float av_l[8][3][C];
  __shared__ float si_l[8][C];
  __shared__ float vi_l[8][3][C];
  __shared__ unsigned wdp_l[C*C];   // 16 KB
  __shared__ unsigned wpp_l[C*C];   // 16 KB
  #pragma unroll
  for (int j = 0; j < 8; ++j){
    wdp_l[t + 512*j] = wdp[t + 512*j];
    wpp_l[t + 512*j] = wpp[t + 512*j];
  }
  as_l[ni][d] = a_s[n*C + d];
  #pragma unroll
  for (int x=0;x<3;x++) av_l[ni][x][d] = a_v[(n*3+x)*C + d];
  si_l[ni][d] = fs_in[n*C + d];
  #pragma unroll
  for (int x=0;x<3;x++) vi_l[ni][x][d] = fv_in[(n*C + d)*3 + x];
  __syncthreads();
  const unsigned* wrp_p = wrp + (size_t)sp*C*C;
  float bs=0, bv0=0, bv1=0, bv2=0, rs=0, rv0=0, rv1=0, rv2=0;
  #pragma unroll 4
  for (int c=0;c<C;++c){
    unsigned ud = wdp_l[c*C+d];
    unsigned ur = wrp_p[c*C+d];
    float wds = unplo(ud), wdv = unphi(ud);
    float wrs = unplo(ur), wrv = unphi(ur);
    bs  += as_l[ni][c]*wds;
    bv0 += av_l[ni][0][c]*wdv; bv1 += av_l[ni][1][c]*wdv; bv2 += av_l[ni][2][c]*wdv;
    rs  += si_l[ni][c]*wrs;
    rv0 += vi_l[ni][0][c]*wrv; rv1 += vi_l[ni][1][c]*wrv; rv2 += vi_l[ni][2][c]*wrv;
  }
  float vv = bv0*bv0 + bv1*bv1 + bv2*bv2;
  float ps  = w1s[sp*C+d]*bs + w2ss[sp*C+d]*bs*bs + w2vv[sp*C+d]*vv;
  float c1v = w1v[sp*C+d], c2sv = w2sv[sp*C+d];
  float pv0 = c1v*bv0 + c2sv*bs*bv0;
  float pv1 = c1v*bv1 + c2sv*bs*bv1;
  float pv2 = c1v*bv2 + c2sv*bs*bv2;
  __syncthreads();
  as_l[ni][d] = ps; av_l[ni][0][d]=pv0; av_l[ni][1][d]=pv1; av_l[ni][2][d]=pv2;
  __syncthreads();
  float qs=0, qv0=0, qv1=0, qv2=0;
  #pragma unroll 4
  for (int c=0;c<C;++c){
    unsigned up = wpp_l[c*C+d];
    float wps = unplo(up), wpv = unphi(up);
    qs  += as_l[ni][c]*wps;
    qv0 += av_l[ni][0][c]*wpv; qv1 += av_l[ni][1][c]*wpv; qv2 += av_l[ni][2][c]*wpv;
  }
  float fsv = qs * phi_f(fabsf(qs)) + rs;
  float nv = sqrtf(qv0*qv0 + qv1*qv1 + qv2*qv2);
  float ph = phi_f(nv);
  float fv0 = qv0*ph + rv0;
  float fv1 = qv1*ph + rv1;
  float fv2 = qv2*ph + rv2;
  out[FS_OFF + n*C + d] = fsv;
  float* fvo = &out[FV_OFF + (size_t)(n*C + d)*3];
  fvo[0]=fv0; fvo[1]=fv1; fvo[2]=fv2;
  #pragma unroll
  for (int h=0; h<HEADS; ++h){
    float r = fsv * w_read[h*C + d];
    #pragma unroll
    for (int off=32; off>0; off>>=1) r += __shfl_down(r, off);
    if (d == 0) out[n*HEADS + h] = r;
  }
}

extern "C" void kernel_launch(void* const* d_in, const int* in_sizes, int n_in,
                              void* d_out, int out_size, void* d_ws, size_t ws_size,
                              hipStream_t stream)
{
  const float* ev   = (const float*)d_in[0];
  const float* nfs  = (const float*)d_in[1];
  const float* nfv  = (const float*)d_in[2];
  const float* re   = (const float*)d_in[3];
  const int*   spec = (const int*)d_in[4];
  const int*   snd  = (const int*)d_in[5];
  const int*   rcv  = (const int*)d_in[6];
  const float* W_rs = (const float*)d_in[7];
  const float* W_rv = (const float*)d_in[8];
  const float* Wus  = (const float*)d_in[9];
  const float* Wuv  = (const float*)d_in[10];
  const float* Wr1  = (const float*)d_in[11];
  const float* Wr2  = (const float*)d_in[12];
  const float* Wds  = (const float*)d_in[13];
  const float* Wdv  = (const float*)d_in[14];
  const float* w1s  = (const float*)d_in[15];
  const float* w1v  = (const float*)d_in[16];
  const float* w2ss = (const float*)d_in[17];
  const float* w2vv = (const float*)d_in[18];
  const float* w2sv = (const float*)d_in[19];
  const float* Wps  = (const float*)d_in[20];
  const float* Wpv  = (const float*)d_in[21];
  const float* wrd  = (const float*)d_in[22];

  float* out = (float*)d_out;
  float* ws  = (float*)d_ws;
  // ws layout (f32 units) — r12 proven layout
  ushort4* suv  = (ushort4*)ws;            // 2,560,000
  float*   a_s  = ws + 2560000;            // 1,280,000
  float*   a_v  = ws + 3840000;            // 3,840,000
  int*    count = (int*)(ws + 7680000);    // 20,000
  int*    cursr = (int*)(ws + 7700000);    // 20,000
  int*    snd_s = (int*)(ws + 7720000);    // 320,000
  int*    rcv_s = (int*)(ws + 8040000);    // 320,000
  float4* u_s   = (float4*)(ws + 8360000); // 1,280,000
  float*  re_s  = ws + 9640000;            // 2,560,000 -> 12,200,000
  unsigned short* wr2t = (unsigned short*)(ws + 12200000);  // -> 12,210,240
  unsigned* wrp = (unsigned*)(ws + 12210240);  // 262,144 -> 12,472,384
  unsigned* wdp = (unsigned*)(ws + 12472384);  // 4,096
  unsigned* wpp = (unsigned*)(ws + 12476480);  // 4,096 -> 12,480,576

  hipMemsetAsync(a_s, 0, (size_t)5120000*sizeof(float), stream);   // a_s + a_v
  hipMemsetAsync(count, 0, (size_t)N_NODES*sizeof(int), stream);

  prep_kernel<<<PREP_BLOCKS, 256, 0, stream>>>(
      Wr2, wr2t, W_rs, W_rv, Wds, Wdv, Wps, Wpv, wrp, wdp, wpp,
      rcv, count, nfs, nfv, Wus, Wuv, suv);
  scan_kernel<<<1, 1024, 0, stream>>>(count, cursr);
  scatter_kernel<<<E_EDGES/256, 256, 0, stream>>>(snd, rcv, ev, re, cursr,
                                                  snd_s, rcv_s, u_s, re_s);
  edge_kernel<<<NPAIR, 512, 0, stream>>>(u_s, re_s, snd_s, rcv_s, Wr1, wr2t,
                                         suv, a_s, a_v);
  node_post_kernel<<<N_NODES/8, 512, 0, stream>>>(a_s, a_v, nfs, nfv, spec,
      wrp, wdp, wpp, w1s, w1v, w2ss, w2vv, w2sv, wrd, out);
}